// Round 2
// baseline (15194.673 us; speedup 1.0000x reference)
//
#include <hip/hip_runtime.h>
#include <hip/hip_bf16.h>

// LSTMblock: B=64, T=1024, I=H=512, L=2.
// R7: latency/transaction-optimized topology.
//   64 WGs x 256 thr: WG = (layer j, 16 h-cols). Each WG covers ALL 64 batch
//   rows; wave w owns rows w*16..w*16+15 and iterates 4 N-tiles (= 4 gates).
//   With mfma_16x16x32 C/D layout (col=lane&15, row=quad*4+reg), N-tile==gate
//   means each lane holds f,i,g,o preacts for its 4 (row,col) cells ->
//   LSTM elementwise fully in-register: no Gbuf LDS exchange, no extra
//   syncthreads, no LDS bank-conflict storm, c-state in 4 regs/lane.
//   h-loads now have zero cross-wave duplication (coherent L3 traffic
//   16MB -> 4MB/step); sync group is 32 WGs (poll traffic ~8x lower).
// R6 (kept): fence-free dataflow. h write-through (sc0 sc1) to bf16 dbuf
//   g_h[j][2][B][H]; producer drains own stores (vmcnt 0) + syncthreads +
//   per-WG flag store; consumers poll flags (sc0 sc1) then batched sc0 sc1
//   h-loads + one vmcnt(0) + sched_barrier(0) before MFMA (rule #18).
//   No buffer_inv/wbl2 anywhere -> L2 stays warm for X and weights.
// R5 (kept): runtime per-tensor dtype detection (some tensors arrive f32).

#define B_ 64
#define T_ 1024
#define I_ 512
#define H_ 512
#define L_ 2

typedef __attribute__((ext_vector_type(8))) short bf16x8;
typedef __attribute__((ext_vector_type(4))) float f32x4;

__device__ unsigned g_flags[2][32][32];                     // 128B line per WG
__device__ __align__(16) unsigned short g_h[L_][2][B_][H_]; // per-layer h dbuf
__device__ int g_isf32[9];                                  // per-input dtype

__device__ __forceinline__ float sigm(float v)  { return 1.f / (1.f + __expf(-v)); }
__device__ __forceinline__ float tanh_(float v) { return 2.f / (1.f + __expf(-2.f * v)) - 1.f; }

__device__ __forceinline__ short f2bs(float x) {
    __hip_bfloat16 h = __float2bfloat16(x);
    return *(short*)&h;
}

// ---- coherent (L1+L2-bypass) access helpers ----
__device__ __forceinline__ void stc_u16(unsigned short* p, unsigned v) {
    asm volatile("global_store_short %0, %1, off sc0 sc1"
                 :: "v"(p), "v"(v) : "memory");
}
__device__ __forceinline__ void stc_u32(unsigned* p, unsigned v) {
    asm volatile("global_store_dword %0, %1, off sc0 sc1"
                 :: "v"(p), "v"(v) : "memory");
}
__device__ __forceinline__ unsigned ldc_u32(const unsigned* p) {
    unsigned r;
    asm volatile("global_load_dword %0, %1, off sc0 sc1\n\ts_waitcnt vmcnt(0)"
                 : "=v"(r) : "v"(p) : "memory");
    return r;
}
// NOTE: no waitcnt inside -- caller MUST s_waitcnt vmcnt(0) + sched_barrier(0)
// before consuming the result.
__device__ __forceinline__ bf16x8 ldc_b128(const unsigned short* p) {
    bf16x8 r;
    asm volatile("global_load_dwordx4 %0, %1, off sc0 sc1"
                 : "=v"(r) : "v"(p) : "memory");
    return r;
}

// 8 consecutive elements at element-offset eoff -> bf16x8 (cvt if f32).
__device__ __forceinline__ bf16x8 ld8(const void* base, size_t eoff, bool isf32) {
    if (!isf32)
        return *(const bf16x8*)((const unsigned short*)base + eoff);
    const float* f = (const float*)base + eoff;
    f32x4 a = *(const f32x4*)f;
    f32x4 b = *(const f32x4*)(f + 4);
    bf16x8 r;
    r[0] = f2bs(a[0]); r[1] = f2bs(a[1]); r[2] = f2bs(a[2]); r[3] = f2bs(a[3]);
    r[4] = f2bs(b[0]); r[5] = f2bs(b[1]); r[6] = f2bs(b[2]); r[7] = f2bs(b[3]);
    return r;
}

__device__ __forceinline__ float ld1(const void* base, size_t eoff, bool isf32) {
    return isf32 ? ((const float*)base)[eoff]
                 : __bfloat162float(((const __hip_bfloat16*)base)[eoff]);
}

__device__ __forceinline__ void st1(void* base, size_t eoff, float v, bool isf32) {
    if (isf32) ((float*)base)[eoff] = v;
    else       ((__hip_bfloat16*)base)[eoff] = __float2bfloat16(v);
}

__global__ __launch_bounds__(576)
void detect_dtypes(const void* t0, const void* t1, const void* t2,
                   const void* t3, const void* t4, const void* t5,
                   const void* t6, const void* t7, const void* t8,
                   int n0, int n1, int n2, int n3, int n4,
                   int n5, int n6, int n7, int n8)
{
    // Reset the per-WG flags for this launch (stream-ordered before lstm;
    // kernel-end implicit release makes these visible).
    for (int i = threadIdx.x; i < 64; i += 576)
        g_flags[i >> 5][i & 31][0] = 0u;

    const void* ts[9] = {t0, t1, t2, t3, t4, t5, t6, t7, t8};
    const int   ns[9] = {n0, n1, n2, n3, n4, n5, n6, n7, n8};
    const int wave = threadIdx.x >> 6;
    const int lane = threadIdx.x & 63;
    if (wave >= 9) return;
    const unsigned* p = (const unsigned*)ts[wave];
    int nw = ns[wave] / 2;            // words safely readable under EITHER dtype
    if (nw > 2048) nw = 2048;
    int cnt = 0;
    for (int i = lane; i < nw; i += 64) {
        unsigned e = (p[i] >> 7) & 0xFFu;   // low ushort's bf16 exponent field
        cnt += (e >= 130u) ? 1 : 0;         // |value| >= 8: impossible for real data
    }
    #pragma unroll
    for (int o = 32; o; o >>= 1) cnt += __shfl_down(cnt, o, 64);
    if (lane == 0) g_isf32[wave] = (cnt > nw / 8) ? 1 : 0;
}

__global__ __launch_bounds__(256)
void lstm_persistent(const void* __restrict__ X,
                     const void* __restrict__ Wf, const void* __restrict__ Bf,
                     const void* __restrict__ Wi, const void* __restrict__ Bi,
                     const void* __restrict__ Wc, const void* __restrict__ Bc,
                     const void* __restrict__ Wo, const void* __restrict__ Bo,
                     void* __restrict__ out)   // ys[B,T,H] | hT[L,B,H] | cT[L,B,H]
{
    // [gate*16 + local_col][k]; row stride 1026 (513 dw == 1 mod 32: B-frag
    // reads land 2..4-way on banks instead of 8-way at 1032). 131,328 B.
    __shared__ ushort Bt[64][1026];

    const int wg   = blockIdx.x;
    const int j    = wg >> 5;         // layer
    const int nb   = wg & 31;         // col-block (16 h-cols)
    const int tid  = threadIdx.x;
    const int lane = tid & 63;
    const int w    = tid >> 6;
    const int quad = lane >> 4;
    const int l15  = lane & 15;
    const int c0   = nb * 16;

    const bool xf  = g_isf32[0] != 0;
    const bool wfl4[4] = {g_isf32[1] != 0, g_isf32[3] != 0,
                          g_isf32[5] != 0, g_isf32[7] != 0};
    const bool bfl4[4] = {g_isf32[2] != 0, g_isf32[4] != 0,
                          g_isf32[6] != 0, g_isf32[8] != 0};
    const bool outf = xf;   // policy: output dtype follows X's

    // ---- stage W slice into LDS, transposed + bf16-converted (one-time) ----
    const void* Ws[4] = {Wf, Wi, Wc, Wo};
    #pragma unroll
    for (int g = 0; g < 4; ++g) {
        for (int idx = tid; idx < 2048; idx += 256) {
            int k = idx >> 1, half = (idx & 1) * 8;
            bf16x8 v = ld8(Ws[g], ((size_t)(j * 1024 + k)) * 512 + c0 + half,
                           wfl4[g]);
            #pragma unroll
            for (int e = 0; e < 8; ++e) Bt[g * 16 + half + e][k] = (ushort)v[e];
        }
    }

    const int colh  = c0 + l15;       // this lane's h-column
    const int rbase = w * 16 + quad * 4;  // C/D rows: rbase+0..3
    const int arow  = w * 16 + l15;       // A-operand row

    const void* Bs[4] = {Bf, Bi, Bc, Bo};
    float bias4[4];
    #pragma unroll
    for (int g = 0; g < 4; ++g) bias4[g] = ld1(Bs[g], j * H_ + colh, bfl4[g]);

    float cst[4] = {0.f, 0.f, 0.f, 0.f};

    __syncthreads();

    for (int t = 0; t < T_; ++t) {
        f32x4 acc[4];
        #pragma unroll
        for (int g = 0; g < 4; ++g) acc[g] = (f32x4){0.f, 0.f, 0.f, 0.f};

        // ---- x-part GEMM (K=512..1023): independent of h(t-1) ----
        {
            const size_t xo = ((size_t)arow * T_ + t) * I_ + quad * 8;
            #pragma unroll
            for (int kk = 0; kk < 16; ++kk) {
                bf16x8 a = ld8(X, xo + kk * 32, xf);
                #pragma unroll
                for (int nt = 0; nt < 4; ++nt) {
                    bf16x8 b = *(const bf16x8*)(&Bt[nt * 16 + l15]
                                                   [512 + kk * 32 + quad * 8]);
                    acc[nt] = __builtin_amdgcn_mfma_f32_16x16x32_bf16(
                                  a, b, acc[nt], 0, 0, 0);
                }
            }
        }

        if (t > 0) {
            // ---- wait for h(t-1): poll the group's 32 flags in parallel ----
            const unsigned* fp = &g_flags[j][lane & 31][0];
            for (;;) {
                unsigned v = ldc_u32(fp);
                if (__all((int)(v >= (unsigned)t))) break;
                __builtin_amdgcn_s_sleep(1);
            }

            // ---- h-part GEMM (K=0..511), coherent batched loads ----
            bf16x8 af[16];
            const unsigned short* hp = &g_h[j][t & 1][arow][quad * 8];
            #pragma unroll
            for (int kk = 0; kk < 16; ++kk) af[kk] = ldc_b128(hp + kk * 32);
            asm volatile("s_waitcnt vmcnt(0)" ::: "memory");
            __builtin_amdgcn_sched_barrier(0);
            #pragma unroll
            for (int kk = 0; kk < 16; ++kk) {
                #pragma unroll
                for (int nt = 0; nt < 4; ++nt) {
                    bf16x8 b = *(const bf16x8*)(&Bt[nt * 16 + l15]
                                                   [kk * 32 + quad * 8]);
                    acc[nt] = __builtin_amdgcn_mfma_f32_16x16x32_bf16(
                                  af[kk], b, acc[nt], 0, 0, 0);
                }
            }
        }
        // t == 0: h0 == 0 -> h-GEMM contributes nothing.

        // ---- in-register LSTM elementwise: lane holds f,i,g,o per cell ----
        #pragma unroll
        for (int r = 0; r < 4; ++r) {
            float fv = sigm (acc[0][r] + bias4[0]);
            float iv = sigm (acc[1][r] + bias4[1]);
            float gv = tanh_(acc[2][r] + bias4[2]);
            float ov = sigm (acc[3][r] + bias4[3]);
            cst[r] = fv * cst[r] + iv * gv;
            float hv = ov * tanh_(cst[r]);
            const int row = rbase + r;

            // h feedback: write-through bf16 (16 lanes x 2B merge to 32B/row)
            stc_u16(&g_h[j][(t + 1) & 1][row][colh],
                    (unsigned)(unsigned short)f2bs(hv));

            if (j == 1)  // ys output only (never read back) -> cached store
                st1(out, ((size_t)row * T_ + t) * H_ + colh, hv, outf);

            if (t == T_ - 1) {
                size_t base = (size_t)B_ * T_ * H_;
                st1(out, base + ((size_t)j * B_ + row) * H_ + colh, hv, outf);
                st1(out, base + (size_t)L_ * B_ * H_
                         + ((size_t)j * B_ + row) * H_ + colh, cst[r], outf);
            }
        }

        // ---- drain own write-through stores, then signal own flag ----
        asm volatile("s_waitcnt vmcnt(0)" ::: "memory");
        __syncthreads();   // all waves' h-stores are at the coherence point
        if (tid == 0 && t < T_ - 1)
            stc_u32(&g_flags[j][nb][0], (unsigned)(t + 1));
    }
}

extern "C" void kernel_launch(void* const* d_in, const int* in_sizes, int n_in,
                              void* d_out, int out_size, void* d_ws, size_t ws_size,
                              hipStream_t stream) {
    const void* X  = d_in[0];
    const void* Wf = d_in[1];  const void* Bf = d_in[2];
    const void* Wi = d_in[3];  const void* Bi = d_in[4];
    const void* Wc = d_in[5];  const void* Bc = d_in[6];
    const void* Wo = d_in[7];  const void* Bo = d_in[8];
    void* out = d_out;

    detect_dtypes<<<dim3(1), dim3(576), 0, stream>>>(
        X, Wf, Bf, Wi, Bi, Wc, Bc, Wo, Bo,
        in_sizes[0], in_sizes[1], in_sizes[2], in_sizes[3], in_sizes[4],
        in_sizes[5], in_sizes[6], in_sizes[7], in_sizes[8]);

    void* args[] = {&X, &Wf, &Bf, &Wi, &Bi, &Wc, &Bc, &Wo, &Bo, &out};
    hipError_t e = hipLaunchCooperativeKernel((const void*)lstm_persistent,
                                              dim3(64), dim3(256), args, 0, stream);
    if (e != hipSuccess) {
        // 64 WGs on 256 CUs are trivially co-resident.
        lstm_persistent<<<dim3(64), dim3(256), 0, stream>>>(
            X, Wf, Bf, Wi, Bi, Wc, Bc, Wo, Bo, out);
    }
}

// Round 3
// 11680.249 us; speedup vs baseline: 1.3009x; 1.3009x over previous
//
#include <hip/hip_runtime.h>
#include <hip/hip_bf16.h>

// LSTMblock: B=64, T=1024, I=H=512, L=2.
// R8: XCD-local sync domains. All recurrent exchange (h dbuf, flags) now
// stays inside ONE XCD's L2 (sc0-only ops ~100-150ns) instead of crossing
// the die to L3 (sc0 sc1, ~300-400ns). Topology: 8 groups = (layer j x
// batch-quarter qb), each group = 32 WGs = exactly one XCD; WG covers
// 16 rows x 16 h-cols x 4 gates; wave w = gate w (32 MFMAs/wave/step).
// Group membership from HW truth: s_getreg(HW_REG_XCC_ID) (measured 0..7
// on MI355X, learn_hip m09) + one startup agent-atomic slot claim. 137KB
// LDS forces 1 WG/CU, so 256 co-resident WGs pigeonhole to exactly 32/XCD.
// Per-wave flags packed in one uint4 line per WG: producer epilogue is
// h-store(sc0) -> vmcnt(0) -> flag(sc0), no syncthreads, no tid0 hop;
// consumers poll the 32 lines (dwordx4, lane-parallel) from local L2.
// ONE __syncthreads per step (Gbuf exchange); Gbuf WAR is protected by the
// flag protocol itself. Cross-replay stale-flag hazard closed by: each WG
// zeroes its OWN flag line locally (sc0), then a one-time grid barrier
// (agent-scope counter, reset by detect_dtypes) before the t-loop.
// R7 post-mortem fixes: Bt row stride back to 1032 ush (516 dw = 4 mod 32,
// 2-way = free for ds_read_b128; 1026 was ~4-way -> +1.3e8 conflicts).
// R6 (kept): fence-free protocol (no wbl2/inv anywhere in the loop).
// R5 (kept): runtime per-tensor dtype detection (tensors may arrive f32).

#define B_ 64
#define T_ 1024
#define I_ 512
#define H_ 512
#define L_ 2

typedef __attribute__((ext_vector_type(8))) short bf16x8;
typedef __attribute__((ext_vector_type(4))) float f32x4;
typedef __attribute__((ext_vector_type(4))) unsigned u32x4;

__device__ __align__(128) unsigned g_flags[8][32][32]; // 128B line per WG
__device__ __align__(16) unsigned short g_h[L_][2][B_][H_]; // per-layer h dbuf
__device__ unsigned g_cnt[8];                          // per-XCD slot counters
__device__ unsigned g_sync;                            // startup grid barrier
__device__ int g_isf32[9];                             // per-input dtype

__device__ __forceinline__ float sigm(float v)  { return 1.f / (1.f + __expf(-v)); }
__device__ __forceinline__ float tanh_(float v) { return 2.f / (1.f + __expf(-2.f * v)) - 1.f; }

__device__ __forceinline__ short f2bs(float x) {
    __hip_bfloat16 h = __float2bfloat16(x);
    return *(short*)&h;
}

// ---- XCD-local coherent helpers: sc0 = L1-bypass, served by the XCD's L2.
// Same-XCD producer/consumer share that L2, so this is coherent inside the
// sync domain (and only there -- grouping is by hardware XCC_ID).
__device__ __forceinline__ void st0_u16(unsigned short* p, unsigned v) {
    asm volatile("global_store_short %0, %1, off sc0"
                 :: "v"(p), "v"(v) : "memory");
}
__device__ __forceinline__ void st0_u32(unsigned* p, unsigned v) {
    asm volatile("global_store_dword %0, %1, off sc0"
                 :: "v"(p), "v"(v) : "memory");
}
__device__ __forceinline__ u32x4 ld0_u32x4(const unsigned* p) {
    u32x4 r;
    asm volatile("global_load_dwordx4 %0, %1, off sc0\n\ts_waitcnt vmcnt(0)"
                 : "=v"(r) : "v"(p) : "memory");
    return r;
}
// NOTE: no waitcnt inside -- caller MUST s_waitcnt vmcnt(0) + sched_barrier(0)
// before consuming the result (rule #18).
__device__ __forceinline__ bf16x8 ld0_b128(const unsigned short* p) {
    bf16x8 r;
    asm volatile("global_load_dwordx4 %0, %1, off sc0"
                 : "=v"(r) : "v"(p) : "memory");
    return r;
}

// 8 consecutive elements at element-offset eoff -> bf16x8 (cvt if f32).
__device__ __forceinline__ bf16x8 ld8(const void* base, size_t eoff, bool isf32) {
    if (!isf32)
        return *(const bf16x8*)((const unsigned short*)base + eoff);
    const float* f = (const float*)base + eoff;
    f32x4 a = *(const f32x4*)f;
    f32x4 b = *(const f32x4*)(f + 4);
    bf16x8 r;
    r[0] = f2bs(a[0]); r[1] = f2bs(a[1]); r[2] = f2bs(a[2]); r[3] = f2bs(a[3]);
    r[4] = f2bs(b[0]); r[5] = f2bs(b[1]); r[6] = f2bs(b[2]); r[7] = f2bs(b[3]);
    return r;
}

__device__ __forceinline__ float ld1(const void* base, size_t eoff, bool isf32) {
    return isf32 ? ((const float*)base)[eoff]
                 : __bfloat162float(((const __hip_bfloat16*)base)[eoff]);
}

__device__ __forceinline__ void st1(void* base, size_t eoff, float v, bool isf32) {
    if (isf32) ((float*)base)[eoff] = v;
    else       ((__hip_bfloat16*)base)[eoff] = __float2bfloat16(v);
}

__global__ __launch_bounds__(576)
void detect_dtypes(const void* t0, const void* t1, const void* t2,
                   const void* t3, const void* t4, const void* t5,
                   const void* t6, const void* t7, const void* t8,
                   int n0, int n1, int n2, int n3, int n4,
                   int n5, int n6, int n7, int n8)
{
    // Per-launch reset (stream-ordered before lstm; kernel-end release
    // flushes these to the coherence point for lstm's agent-scope atomics).
    unsigned* fz = &g_flags[0][0][0];
    for (int i = threadIdx.x; i < 8 * 32 * 32; i += 576) fz[i] = 0u;
    if (threadIdx.x < 8) g_cnt[threadIdx.x] = 0u;
    if (threadIdx.x == 8) g_sync = 0u;

    const void* ts[9] = {t0, t1, t2, t3, t4, t5, t6, t7, t8};
    const int   ns[9] = {n0, n1, n2, n3, n4, n5, n6, n7, n8};
    const int wave = threadIdx.x >> 6;
    const int lane = threadIdx.x & 63;
    if (wave >= 9) return;
    const unsigned* p = (const unsigned*)ts[wave];
    int nw = ns[wave] / 2;            // words safely readable under EITHER dtype
    if (nw > 2048) nw = 2048;
    int cnt = 0;
    for (int i = lane; i < nw; i += 64) {
        unsigned e = (p[i] >> 7) & 0xFFu;   // low ushort's bf16 exponent field
        cnt += (e >= 130u) ? 1 : 0;         // |value| >= 8: impossible for real data
    }
    #pragma unroll
    for (int o = 32; o; o >>= 1) cnt += __shfl_down(cnt, o, 64);
    if (lane == 0) g_isf32[wave] = (cnt > nw / 8) ? 1 : 0;
}

__global__ __launch_bounds__(256)
void lstm_persistent(const void* __restrict__ X,
                     const void* __restrict__ Wf, const void* __restrict__ Bf,
                     const void* __restrict__ Wi, const void* __restrict__ Bi,
                     const void* __restrict__ Wc, const void* __restrict__ Bc,
                     const void* __restrict__ Wo, const void* __restrict__ Bo,
                     void* __restrict__ out)   // ys[B,T,H] | hT[L,B,H] | cT[L,B,H]
{
    // [gate*16 + local_col][k]; stride 1032 ush = 516 dw == 4 (mod 32):
    // b128 reads are 2-way on banks (free, m136). 16B-aligned rows. 132,096B.
    __shared__ ushort Bt[64][1032];
    __shared__ float  Gbuf[4][16][17];   // [gate][row][col] preacts, 4,352B
    __shared__ int    sh_slot;

    const int tid  = threadIdx.x;
    const int lane = tid & 63;
    const int w    = tid >> 6;        // wave = gate
    const int quad = lane >> 4;
    const int l15  = lane & 15;

    // ---- hardware group identity: XCD id -> (layer, batch-quarter) ----
    unsigned xcc;
    asm volatile("s_getreg_b32 %0, hwreg(HW_REG_XCC_ID, 0, 32)" : "=s"(xcc));
    xcc &= 7u;
    const int j  = (int)(xcc >> 2);   // layer
    const int qb = (int)(xcc & 3);    // 16-row batch quarter

    if (tid == 0)
        sh_slot = (int)__hip_atomic_fetch_add(&g_cnt[xcc], 1u,
                        __ATOMIC_RELAXED, __HIP_MEMORY_SCOPE_AGENT);
    __syncthreads();
    const int nb = sh_slot & 31;      // col-block 0..31 (mask = OOB guard)
    const int c0 = nb * 16;

    // Zero OWN flag line in the LOCAL L2 (kills stale lines from previous
    // graph replays; consumers only ever read it from this same L2).
    if (tid < 4) st0_u32(&g_flags[xcc][nb][tid], 0u);
    asm volatile("s_waitcnt vmcnt(0)" ::: "memory");

    const bool xf  = g_isf32[0] != 0;
    const bool wfl4[4] = {g_isf32[1] != 0, g_isf32[3] != 0,
                          g_isf32[5] != 0, g_isf32[7] != 0};
    const bool bfl4[4] = {g_isf32[2] != 0, g_isf32[4] != 0,
                          g_isf32[6] != 0, g_isf32[8] != 0};
    const bool outf = xf;   // policy: output dtype follows X's

    // ---- stage W slice into LDS, transposed + bf16-converted (one-time) ----
    const void* Ws[4] = {Wf, Wi, Wc, Wo};
    #pragma unroll
    for (int g = 0; g < 4; ++g) {
        for (int idx = tid; idx < 2048; idx += 256) {
            int k = idx >> 1, half = (idx & 1) * 8;
            bf16x8 v = ld8(Ws[g], ((size_t)(j * 1024 + k)) * 512 + c0 + half,
                           wfl4[g]);
            #pragma unroll
            for (int e = 0; e < 8; ++e) Bt[g * 16 + half + e][k] = (ushort)v[e];
        }
    }

    const int   r_ew = tid >> 4;      // elementwise cell row 0..15
    const int   c_ew = tid & 15;      // elementwise cell col 0..15
    const int   colh = c0 + c_ew;
    const void* Bs[4] = {Bf, Bi, Bc, Bo};
    float bias4[4];
    #pragma unroll
    for (int g = 0; g < 4; ++g) bias4[g] = ld1(Bs[g], j * H_ + colh, bfl4[g]);
    float cst = 0.f;

    __syncthreads();   // weights staged

    // ---- one-time grid barrier: no WG may signal step-0 before every WG
    // has zeroed its flag line (agent-scope counter, reset each launch) ----
    if (tid == 0) {
        __hip_atomic_fetch_add(&g_sync, 1u, __ATOMIC_RELAXED,
                               __HIP_MEMORY_SCOPE_AGENT);
        for (int it = 0; it < (1 << 23); ++it) {
            if (__hip_atomic_load(&g_sync, __ATOMIC_RELAXED,
                                  __HIP_MEMORY_SCOPE_AGENT) >= 256u) break;
            __builtin_amdgcn_s_sleep(8);
        }
    }
    __syncthreads();

    for (int t = 0; t < T_; ++t) {
        f32x4 accA = {0.f, 0.f, 0.f, 0.f};
        f32x4 accB = {0.f, 0.f, 0.f, 0.f};

        // ---- x-part GEMM (K=512..1023): independent of h(t-1).
        // All 4 waves read the same 16 X rows -> dup served by L1. ----
        {
            const size_t xo = ((size_t)(qb * 16 + l15) * T_ + t) * I_ + quad * 8;
            #pragma unroll
            for (int kk = 0; kk < 16; kk += 2) {
                bf16x8 a0 = ld8(X, xo + kk * 32, xf);
                bf16x8 a1 = ld8(X, xo + (kk + 1) * 32, xf);
                bf16x8 b0 = *(const bf16x8*)(&Bt[w * 16 + l15]
                                                [512 + kk * 32 + quad * 8]);
                bf16x8 b1 = *(const bf16x8*)(&Bt[w * 16 + l15]
                                                [512 + (kk + 1) * 32 + quad * 8]);
                accA = __builtin_amdgcn_mfma_f32_16x16x32_bf16(a0, b0, accA, 0, 0, 0);
                accB = __builtin_amdgcn_mfma_f32_16x16x32_bf16(a1, b1, accB, 0, 0, 0);
            }
        }

        if (t > 0) {
            // ---- wait for h(t-1): poll group's 32 flag lines, lane-parallel,
            // all from the LOCAL L2 ----
            const unsigned* fp = &g_flags[xcc][lane & 31][0];
            for (int it = 0; it < (1 << 22); ++it) {
                u32x4 v = ld0_u32x4(fp);
                unsigned m0 = v[0] < v[1] ? v[0] : v[1];
                unsigned m1 = v[2] < v[3] ? v[2] : v[3];
                unsigned mn = m0 < m1 ? m0 : m1;
                if (__all((int)(mn >= (unsigned)t))) break;
                __builtin_amdgcn_s_sleep(1);
            }

            // ---- h-part GEMM (K=0..511), batched local-L2 loads ----
            bf16x8 af[16];
            const unsigned short* hp = &g_h[j][t & 1][qb * 16 + l15][quad * 8];
            #pragma unroll
            for (int kk = 0; kk < 16; ++kk) af[kk] = ld0_b128(hp + kk * 32);
            asm volatile("s_waitcnt vmcnt(0)" ::: "memory");
            __builtin_amdgcn_sched_barrier(0);
            #pragma unroll
            for (int kk = 0; kk < 16; kk += 2) {
                bf16x8 b0 = *(const bf16x8*)(&Bt[w * 16 + l15]
                                                [kk * 32 + quad * 8]);
                bf16x8 b1 = *(const bf16x8*)(&Bt[w * 16 + l15]
                                                [(kk + 1) * 32 + quad * 8]);
                accA = __builtin_amdgcn_mfma_f32_16x16x32_bf16(af[kk], b0, accA, 0, 0, 0);
                accB = __builtin_amdgcn_mfma_f32_16x16x32_bf16(af[kk + 1], b1, accB, 0, 0, 0);
            }
        }
        // t == 0: h0 == 0 -> h-GEMM contributes nothing.

        // ---- cross-wave gate exchange (wave w holds gate w's 16x16 tile) ----
        #pragma unroll
        for (int r = 0; r < 4; ++r)
            Gbuf[w][quad * 4 + r][l15] = accA[r] + accB[r];
        __syncthreads();
        // (Next step's Gbuf writes can't race these reads: they require
        // poll(t+1), which requires THIS WG's flag t+1, set below after the
        // elementwise reads are done.)

        // ---- in-register LSTM cell update: one cell per thread ----
        float fv = sigm (Gbuf[0][r_ew][c_ew] + bias4[0]);
        float iv = sigm (Gbuf[1][r_ew][c_ew] + bias4[1]);
        float gv = tanh_(Gbuf[2][r_ew][c_ew] + bias4[2]);
        float ov = sigm (Gbuf[3][r_ew][c_ew] + bias4[3]);
        cst = fv * cst + iv * gv;
        float hv = ov * tanh_(cst);
        const int row = qb * 16 + r_ew;

        // h feedback: bf16 store into local L2 (sc0), drain, per-wave flag.
        st0_u16(&g_h[j][(t + 1) & 1][row][colh],
                (unsigned)(unsigned short)f2bs(hv));
        asm volatile("s_waitcnt vmcnt(0)" ::: "memory");
        if (lane == 0 && t + 1 < T_)
            st0_u32(&g_flags[xcc][nb][w], (unsigned)(t + 1));

        if (j == 1)  // ys output only (never read back) -> cached store
            st1(out, ((size_t)row * T_ + t) * H_ + colh, hv, outf);

        if (t == T_ - 1) {
            size_t base = (size_t)B_ * T_ * H_;
            st1(out, base + ((size_t)j * B_ + row) * H_ + colh, hv, outf);
            st1(out, base + (size_t)L_ * B_ * H_
                     + ((size_t)j * B_ + row) * H_ + colh, cst, outf);
        }
    }
}

extern "C" void kernel_launch(void* const* d_in, const int* in_sizes, int n_in,
                              void* d_out, int out_size, void* d_ws, size_t ws_size,
                              hipStream_t stream) {
    const void* X  = d_in[0];
    const void* Wf = d_in[1];  const void* Bf = d_in[2];
    const void* Wi = d_in[3];  const void* Bi = d_in[4];
    const void* Wc = d_in[5];  const void* Bc = d_in[6];
    const void* Wo = d_in[7];  const void* Bo = d_in[8];
    void* out = d_out;

    detect_dtypes<<<dim3(1), dim3(576), 0, stream>>>(
        X, Wf, Bf, Wi, Bi, Wc, Bc, Wo, Bo,
        in_sizes[0], in_sizes[1], in_sizes[2], in_sizes[3], in_sizes[4],
        in_sizes[5], in_sizes[6], in_sizes[7], in_sizes[8]);

    void* args[] = {&X, &Wf, &Bf, &Wi, &Bi, &Wc, &Bc, &Wo, &Bo, &out};
    hipError_t e = hipLaunchCooperativeKernel((const void*)lstm_persistent,
                                              dim3(256), dim3(256), args, 0, stream);
    if (e != hipSuccess) {
        // 256 WGs at 1 WG/CU (137KB LDS) are co-resident on 256 CUs anyway.
        lstm_persistent<<<dim3(256), dim3(256), 0, stream>>>(
            X, Wf, Bf, Wi, Bi, Wc, Bc, Wo, Bo, out);
    }
}

// Round 4
// 5112.139 us; speedup vs baseline: 2.9723x; 2.2848x over previous
//
#include <hip/hip_runtime.h>
#include <hip/hip_bf16.h>

// LSTMblock: B=64, T=1024, I=H=512, L=2.
// R9: anti-poll-storm + X off the serial path.
//   - Sync: ONE counter word per group (g_step[xcc]). Arrive = tid0
//     global_atomic_add WITHOUT sc1 (executes in the XCD's local L2 atomic
//     unit -- group members all live on that XCD, so local-L2 atomicity is
//     exactly the needed scope). Poll = lane-uniform sc0 load of one word
//     (1 L2 sector request per wave per iter, s_sleep(2) backoff). R8's
//     128 waves x 32-sector flag scans (~30 req/cy) saturated the L2 and
//     inflated every hop; R6 had the same storm against L3 -> same 11-12ms.
//   - X path: one-time convert kernel X(f32)->g_Xbf(bf16) (skipped if X is
//     already bf16); per-step A-fragments register-prefetched (16 x b128,
//     64 VGPR) right after the current x-GEMM consumes them, so L3 latency
//     hides under poll + h-GEMM. Removes ~256 cvt VALU ops + 32 L3-latency
//     loads from the per-step serial chain.
// R8 (kept): XCD-local domains via s_getreg(XCC_ID) + slot claim; 8 groups =
//   (layer j x batch-quarter qb) of 32 WGs = 1 XCD; wave=gate; Gbuf gate
//   exchange; g_h bf16 dbuf with sc0 write-through + vmcnt(0) drain; local
//   counter zero + one-time grid barrier for replay safety; Bt stride 1032
//   (516 dw = 4 mod 32 -> 2-way = free).
// R5 (kept): runtime per-tensor dtype detection.

#define B_ 64
#define T_ 1024
#define I_ 512
#define H_ 512
#define L_ 2

typedef __attribute__((ext_vector_type(8))) short bf16x8;
typedef __attribute__((ext_vector_type(4))) float f32x4;

__device__ __align__(128) unsigned g_step[8][32];           // 1 line per group
__device__ __align__(16) unsigned short g_h[L_][2][B_][H_]; // per-layer h dbuf
__device__ __align__(16) unsigned short g_Xbf[B_][T_][I_];  // X as bf16 (67MB)
__device__ unsigned g_cnt[8];                               // per-XCD slot ctr
__device__ unsigned g_sync;                                 // startup barrier
__device__ int g_isf32[9];                                  // per-input dtype

__device__ __forceinline__ float sigm(float v)  { return 1.f / (1.f + __expf(-v)); }
__device__ __forceinline__ float tanh_(float v) { return 2.f / (1.f + __expf(-2.f * v)) - 1.f; }

__device__ __forceinline__ short f2bs(float x) {
    __hip_bfloat16 h = __float2bfloat16(x);
    return *(short*)&h;
}

// ---- XCD-local coherent helpers (sc0 = L1-bypass, served by local L2) ----
__device__ __forceinline__ void st0_u16(unsigned short* p, unsigned v) {
    asm volatile("global_store_short %0, %1, off sc0"
                 :: "v"(p), "v"(v) : "memory");
}
__device__ __forceinline__ void st0_u32(unsigned* p, unsigned v) {
    asm volatile("global_store_dword %0, %1, off sc0"
                 :: "v"(p), "v"(v) : "memory");
}
__device__ __forceinline__ unsigned ld0_u32(const unsigned* p) {
    unsigned r;
    asm volatile("global_load_dword %0, %1, off sc0\n\ts_waitcnt vmcnt(0)"
                 : "=v"(r) : "v"(p) : "memory");
    return r;
}
// Fire-and-forget add executed in the LOCAL L2's atomic unit (no sc1: stays
// at this XCD's coherence point -- all group members share it).
__device__ __forceinline__ void atom_add_l2(unsigned* p, unsigned v) {
    asm volatile("global_atomic_add %0, %1, off"
                 :: "v"(p), "v"(v) : "memory");
}
// NOTE: no waitcnt inside -- caller MUST s_waitcnt vmcnt(0) + sched_barrier(0)
// before consuming the result (rule #18).
__device__ __forceinline__ bf16x8 ld0_b128(const unsigned short* p) {
    bf16x8 r;
    asm volatile("global_load_dwordx4 %0, %1, off sc0"
                 : "=v"(r) : "v"(p) : "memory");
    return r;
}

// 8 consecutive elements at element-offset eoff -> bf16x8 (cvt if f32).
__device__ __forceinline__ bf16x8 ld8(const void* base, size_t eoff, bool isf32) {
    if (!isf32)
        return *(const bf16x8*)((const unsigned short*)base + eoff);
    const float* f = (const float*)base + eoff;
    f32x4 a = *(const f32x4*)f;
    f32x4 b = *(const f32x4*)(f + 4);
    bf16x8 r;
    r[0] = f2bs(a[0]); r[1] = f2bs(a[1]); r[2] = f2bs(a[2]); r[3] = f2bs(a[3]);
    r[4] = f2bs(b[0]); r[5] = f2bs(b[1]); r[6] = f2bs(b[2]); r[7] = f2bs(b[3]);
    return r;
}

__device__ __forceinline__ float ld1(const void* base, size_t eoff, bool isf32) {
    return isf32 ? ((const float*)base)[eoff]
                 : __bfloat162float(((const __hip_bfloat16*)base)[eoff]);
}

__device__ __forceinline__ void st1(void* base, size_t eoff, float v, bool isf32) {
    if (isf32) ((float*)base)[eoff] = v;
    else       ((__hip_bfloat16*)base)[eoff] = __float2bfloat16(v);
}

__global__ __launch_bounds__(576)
void detect_dtypes(const void* t0, const void* t1, const void* t2,
                   const void* t3, const void* t4, const void* t5,
                   const void* t6, const void* t7, const void* t8,
                   int n0, int n1, int n2, int n3, int n4,
                   int n5, int n6, int n7, int n8)
{
    // Per-launch reset (stream-ordered before lstm; kernel-boundary cache
    // maintenance makes these visible to lstm on every XCD).
    if (threadIdx.x < 8)  g_cnt[threadIdx.x] = 0u;
    if (threadIdx.x == 8) g_sync = 0u;
    if (threadIdx.x < 8)  g_step[threadIdx.x][0] = 0u;

    const void* ts[9] = {t0, t1, t2, t3, t4, t5, t6, t7, t8};
    const int   ns[9] = {n0, n1, n2, n3, n4, n5, n6, n7, n8};
    const int wave = threadIdx.x >> 6;
    const int lane = threadIdx.x & 63;
    if (wave >= 9) return;
    const unsigned* p = (const unsigned*)ts[wave];
    int nw = ns[wave] / 2;            // words safely readable under EITHER dtype
    if (nw > 2048) nw = 2048;
    int cnt = 0;
    for (int i = lane; i < nw; i += 64) {
        unsigned e = (p[i] >> 7) & 0xFFu;   // low ushort's bf16 exponent field
        cnt += (e >= 130u) ? 1 : 0;         // |value| >= 8: impossible for real data
    }
    #pragma unroll
    for (int o = 32; o; o >>= 1) cnt += __shfl_down(cnt, o, 64);
    if (lane == 0) g_isf32[wave] = (cnt > nw / 8) ? 1 : 0;
}

__global__ __launch_bounds__(256)
void convert_x(const void* __restrict__ X)
{
    if (!g_isf32[0]) return;   // X already bf16: lstm reads it directly
    const float* src = (const float*)X;
    unsigned short* dst = &g_Xbf[0][0][0];
    const size_t n = (size_t)B_ * T_ * I_;
    for (size_t i = ((size_t)blockIdx.x * 256 + threadIdx.x) * 8; i < n;
         i += (size_t)gridDim.x * 256 * 8) {
        f32x4 a = *(const f32x4*)(src + i);
        f32x4 b = *(const f32x4*)(src + i + 4);
        bf16x8 r;
        r[0] = f2bs(a[0]); r[1] = f2bs(a[1]); r[2] = f2bs(a[2]); r[3] = f2bs(a[3]);
        r[4] = f2bs(b[0]); r[5] = f2bs(b[1]); r[6] = f2bs(b[2]); r[7] = f2bs(b[3]);
        *(bf16x8*)(dst + i) = r;
    }
}

__global__ __launch_bounds__(256, 1)
void lstm_persistent(const void* __restrict__ X,
                     const void* __restrict__ Wf, const void* __restrict__ Bf,
                     const void* __restrict__ Wi, const void* __restrict__ Bi,
                     const void* __restrict__ Wc, const void* __restrict__ Bc,
                     const void* __restrict__ Wo, const void* __restrict__ Bo,
                     void* __restrict__ out)   // ys[B,T,H] | hT[L,B,H] | cT[L,B,H]
{
    // [gate*16 + local_col][k]; stride 1032 ush = 516 dw == 4 (mod 32):
    // b128 reads are 2-way on banks (free, m136). 132,096 B.
    __shared__ ushort Bt[64][1032];
    __shared__ float  Gbuf[4][16][17];   // [gate][row][col] preacts
    __shared__ int    sh_slot;

    const int tid  = threadIdx.x;
    const int lane = tid & 63;
    const int w    = tid >> 6;        // wave = gate
    const int quad = lane >> 4;
    const int l15  = lane & 15;

    // ---- hardware group identity: XCD id -> (layer, batch-quarter) ----
    unsigned xcc;
    asm volatile("s_getreg_b32 %0, hwreg(HW_REG_XCC_ID, 0, 32)" : "=s"(xcc));
    xcc &= 7u;
    const int j  = (int)(xcc >> 2);   // layer
    const int qb = (int)(xcc & 3);    // 16-row batch quarter

    if (tid == 0)
        sh_slot = (int)__hip_atomic_fetch_add(&g_cnt[xcc], 1u,
                        __ATOMIC_RELAXED, __HIP_MEMORY_SCOPE_AGENT);
    __syncthreads();
    const int nb = sh_slot & 31;      // col-block 0..31 (mask = OOB guard)
    const int c0 = nb * 16;

    // Zero the group counter in the LOCAL L2 (kills stale lines from prior
    // replays; consumers only ever read it from this same L2).
    if (nb == 0 && tid == 0) st0_u32(&g_step[xcc][0], 0u);
    asm volatile("s_waitcnt vmcnt(0)" ::: "memory");

    const bool xf  = g_isf32[0] != 0;
    const bool wfl4[4] = {g_isf32[1] != 0, g_isf32[3] != 0,
                          g_isf32[5] != 0, g_isf32[7] != 0};
    const bool bfl4[4] = {g_isf32[2] != 0, g_isf32[4] != 0,
                          g_isf32[6] != 0, g_isf32[8] != 0};
    const bool outf = xf;   // policy: output dtype follows X's

    // ---- stage W slice into LDS, transposed + bf16-converted (one-time) ----
    const void* Ws[4] = {Wf, Wi, Wc, Wo};
    #pragma unroll
    for (int g = 0; g < 4; ++g) {
        for (int idx = tid; idx < 2048; idx += 256) {
            int k = idx >> 1, half = (idx & 1) * 8;
            bf16x8 v = ld8(Ws[g], ((size_t)(j * 1024 + k)) * 512 + c0 + half,
                           wfl4[g]);
            #pragma unroll
            for (int e = 0; e < 8; ++e) Bt[g * 16 + half + e][k] = (ushort)v[e];
        }
    }

    const int   r_ew = tid >> 4;      // elementwise cell row 0..15
    const int   c_ew = tid & 15;      // elementwise cell col 0..15
    const int   colh = c0 + c_ew;
    const void* Bs[4] = {Bf, Bi, Bc, Bo};
    float bias4[4];
    #pragma unroll
    for (int g = 0; g < 4; ++g) bias4[g] = ld1(Bs[g], j * H_ + colh, bfl4[g]);
    float cst = 0.f;

    __syncthreads();   // weights staged

    // ---- one-time grid barrier: no WG may arrive for step 0 before every
    // group's counter is zeroed (agent-scope counter, reset each launch) ----
    if (tid == 0) {
        __hip_atomic_fetch_add(&g_sync, 1u, __ATOMIC_RELAXED,
                               __HIP_MEMORY_SCOPE_AGENT);
        for (int it = 0; it < (1 << 23); ++it) {
            if (__hip_atomic_load(&g_sync, __ATOMIC_RELAXED,
                                  __HIP_MEMORY_SCOPE_AGENT) >= 256u) break;
            __builtin_amdgcn_s_sleep(8);
        }
    }
    __syncthreads();

    // ---- X source: bf16 view (pre-converted if X arrived f32) ----
    const unsigned short* Xs =
        xf ? &g_Xbf[0][0][0] : (const unsigned short*)X;
    const size_t xrowoff = (size_t)(qb * 16 + l15) * T_;   // this lane's row

    // Prologue prefetch of step-0 A-fragments (16 x b128 = 64 VGPR).
    bf16x8 xr[16];
    {
        const unsigned short* xp = Xs + (xrowoff + 0) * I_ + quad * 8;
        #pragma unroll
        for (int kk = 0; kk < 16; ++kk)
            xr[kk] = *(const bf16x8*)(xp + kk * 32);
    }

    unsigned* const sp = &g_step[xcc][0];

    for (int t = 0; t < T_; ++t) {
        f32x4 accA = {0.f, 0.f, 0.f, 0.f};
        f32x4 accB = {0.f, 0.f, 0.f, 0.f};

        // ---- x-part GEMM (K=512..1023) from prefetched registers ----
        #pragma unroll
        for (int kk = 0; kk < 16; kk += 2) {
            bf16x8 b0 = *(const bf16x8*)(&Bt[w * 16 + l15]
                                            [512 + kk * 32 + quad * 8]);
            bf16x8 b1 = *(const bf16x8*)(&Bt[w * 16 + l15]
                                            [512 + (kk + 1) * 32 + quad * 8]);
            accA = __builtin_amdgcn_mfma_f32_16x16x32_bf16(xr[kk], b0, accA, 0, 0, 0);
            accB = __builtin_amdgcn_mfma_f32_16x16x32_bf16(xr[kk + 1], b1, accB, 0, 0, 0);
        }

        // ---- issue next step's X prefetch (L3 latency hides under
        // poll + h-GEMM; WAR on xr resolved by the compiler) ----
        {
            const int tp = (t + 1 < T_) ? t + 1 : t;
            const unsigned short* xp = Xs + (xrowoff + tp) * I_ + quad * 8;
            #pragma unroll
            for (int kk = 0; kk < 16; ++kk)
                xr[kk] = *(const bf16x8*)(xp + kk * 32);
        }

        if (t > 0) {
            // ---- wait for h(t-1): lane-uniform poll of ONE local-L2 word ----
            const unsigned tgt = 32u * (unsigned)t;
            for (int it = 0; it < (1 << 22); ++it) {
                unsigned v = ld0_u32(sp);
                if (v >= tgt) break;
                __builtin_amdgcn_s_sleep(2);
            }

            // ---- h-part GEMM (K=0..511), batched local-L2 loads ----
            bf16x8 af[16];
            const unsigned short* hp = &g_h[j][t & 1][qb * 16 + l15][quad * 8];
            #pragma unroll
            for (int kk = 0; kk < 16; ++kk) af[kk] = ld0_b128(hp + kk * 32);
            asm volatile("s_waitcnt vmcnt(0)" ::: "memory");
            __builtin_amdgcn_sched_barrier(0);
            #pragma unroll
            for (int kk = 0; kk < 16; kk += 2) {
                bf16x8 b0 = *(const bf16x8*)(&Bt[w * 16 + l15]
                                                [kk * 32 + quad * 8]);
                bf16x8 b1 = *(const bf16x8*)(&Bt[w * 16 + l15]
                                                [(kk + 1) * 32 + quad * 8]);
                accA = __builtin_amdgcn_mfma_f32_16x16x32_bf16(af[kk], b0, accA, 0, 0, 0);
                accB = __builtin_amdgcn_mfma_f32_16x16x32_bf16(af[kk + 1], b1, accB, 0, 0, 0);
            }
        }
        // t == 0: h0 == 0 -> h-GEMM contributes nothing.

        // ---- cross-wave gate exchange (wave w holds gate w's 16x16 tile) ----
        #pragma unroll
        for (int r = 0; r < 4; ++r)
            Gbuf[w][quad * 4 + r][l15] = accA[r] + accB[r];
        __syncthreads();

        // ---- LSTM cell update: one cell per thread ----
        float fv = sigm (Gbuf[0][r_ew][c_ew] + bias4[0]);
        float iv = sigm (Gbuf[1][r_ew][c_ew] + bias4[1]);
        float gv = tanh_(Gbuf[2][r_ew][c_ew] + bias4[2]);
        float ov = sigm (Gbuf[3][r_ew][c_ew] + bias4[3]);
        cst = fv * cst + iv * gv;
        float hv = ov * tanh_(cst);
        const int row = qb * 16 + r_ew;

        // h feedback: bf16 store into local L2 (sc0).
        st0_u16(&g_h[j][(t + 1) & 1][row][colh],
                (unsigned)(unsigned short)f2bs(hv));

        if (j == 1)  // ys output only (never read back) -> cached store
            st1(out, ((size_t)row * T_ + t) * H_ + colh, hv, outf);

        if (t == T_ - 1) {
            size_t base = (size_t)B_ * T_ * H_;
            st1(out, base + ((size_t)j * B_ + row) * H_ + colh, hv, outf);
            st1(out, base + (size_t)L_ * B_ * H_
                     + ((size_t)j * B_ + row) * H_ + colh, cst, outf);
        }

        // ---- drain stores, WG-arrive on the group counter ----
        asm volatile("s_waitcnt vmcnt(0)" ::: "memory");
        __syncthreads();   // all waves' h-stores are at the coherence point;
                           // also closes the Gbuf WAR for the next step
        if (tid == 0 && t + 1 < T_)
            atom_add_l2(sp, 1u);
    }
}

extern "C" void kernel_launch(void* const* d_in, const int* in_sizes, int n_in,
                              void* d_out, int out_size, void* d_ws, size_t ws_size,
                              hipStream_t stream) {
    const void* X  = d_in[0];
    const void* Wf = d_in[1];  const void* Bf = d_in[2];
    const void* Wi = d_in[3];  const void* Bi = d_in[4];
    const void* Wc = d_in[5];  const void* Bc = d_in[6];
    const void* Wo = d_in[7];  const void* Bo = d_in[8];
    void* out = d_out;

    detect_dtypes<<<dim3(1), dim3(576), 0, stream>>>(
        X, Wf, Bf, Wi, Bi, Wc, Bc, Wo, Bo,
        in_sizes[0], in_sizes[1], in_sizes[2], in_sizes[3], in_sizes[4],
        in_sizes[5], in_sizes[6], in_sizes[7], in_sizes[8]);

    convert_x<<<dim3(2048), dim3(256), 0, stream>>>(X);

    void* args[] = {&X, &Wf, &Bf, &Wi, &Bi, &Wc, &Bc, &Wo, &Bo, &out};
    hipError_t e = hipLaunchCooperativeKernel((const void*)lstm_persistent,
                                              dim3(256), dim3(256), args, 0, stream);
    if (e != hipSuccess) {
        // 256 WGs at 1 WG/CU (137KB LDS) are co-resident on 256 CUs anyway.
        lstm_persistent<<<dim3(256), dim3(256), 0, stream>>>(
            X, Wf, Bf, Wi, Bi, Wc, Bc, Wo, Bo, out);
    }
}